// Round 11
// baseline (200.609 us; speedup 1.0000x reference)
//
#include <hip/hip_runtime.h>

typedef unsigned long long u64;
typedef unsigned int u32;

#define BDIM 16
#define NP   4096
#define NC   91
#define NCM1 90
#define MSEL 4096       // top-M per image (reference M)
#define NSORT 1024      // batch-0 sorted prefix size
#define KOUT 100
#define RSLOT 19        // max candidates per row (scores sum to 1, >0.05 => <=19)
#define RPB 64          // rows per k_soft block (64 blocks per image)
#define STRIDE (RPB * RSLOT)     // 1216 slots per block region
#define CAP_D (NP * RSLOT)       // 77824 = 64 * STRIDE per image
#define SCORE_T 0.05f
#define NMS_T   0.5f
#define OFFSETF 10000.0f
#define DW_CLAMP_F 4.135166556742356f
#define WF 1333.0f
#define HF 800.0f

#define TN 1024
#define NW (TN / 64)      // 16 waves

// ---------------- Kernel 1: softmax -> per-block-region dense candidates (no atomics, no init) ----------------
// Block blk owns dense[blk*STRIDE .. +cnt); blkcnt[blk] written unconditionally every call.
// Region order is deterministic; downstream histogram (commutative) and bitonic sort
// (distinct keys) canonicalize -> output bit-deterministic.
__global__ __launch_bounds__(256) void k_soft(const float* __restrict__ logits,
                                              u64* __restrict__ dense,
                                              int* __restrict__ blkcnt) {
    __shared__ u64 stage[STRIDE];        // 1216 keys max (block's provable cap) = 9.5 KB
    __shared__ int s_cnt;

    int blk  = blockIdx.x;               // 1024 blocks; 64 consecutive rows each
    int lane = threadIdx.x & 63;
    int wid  = threadIdx.x >> 6;

    if (threadIdx.x == 0) s_cnt = 0;
    __syncthreads();

    u64 lm = (1ull << lane) - 1ull;
    for (int it = 0; it < RPB / 4; ++it) {
        int row = blk * RPB + it * 4 + wid;          // one wave per row
        const float* lg = logits + (long)row * NC;

        float v0 = lg[lane];
        float v1 = (lane < NC - 64) ? lg[64 + lane] : -3.0e38f;
        float mx = fmaxf(v0, v1);
#pragma unroll
        for (int s = 32; s; s >>= 1) mx = fmaxf(mx, __shfl_xor(mx, s));
        float e0 = expf(v0 - mx);
        float e1 = (lane < NC - 64) ? expf(v1 - mx) : 0.0f;
        float sum = e0 + e1;
#pragma unroll
        for (int s = 32; s; s >>= 1) sum += __shfl_xor(sum, s);

        float s0 = e0 / sum;
        float s1 = e1 / sum;

        int n = row & (NP - 1);
        bool p0 = (lane >= 1) && (s0 > SCORE_T);          // class = lane (skip background 0)
        bool p1 = (lane < NC - 64) && (s1 > SCORE_T);     // class = 64 + lane
        u64 m0 = __ballot(p0);
        u64 m1 = __ballot(p1);
        int c0  = __popcll(m0);
        int cnt = c0 + __popcll(m1);

        int base = 0;
        if (lane == 0 && cnt) base = atomicAdd(&s_cnt, cnt);   // LDS atomic, 1/wave/row
        base = __shfl(base, 0);
        if (p0) {
            int pos  = base + __popcll(m0 & lm);
            int flat = n * NCM1 + (lane - 1);
            stage[pos] = ((u64)__float_as_uint(s0) << 32) | (u32)(~(u32)flat);
        }
        if (p1) {
            int pos  = base + c0 + __popcll(m1 & lm);
            int flat = n * NCM1 + (64 + lane - 1);
            stage[pos] = ((u64)__float_as_uint(s1) << 32) | (u32)(~(u32)flat);
        }
    }
    __syncthreads();

    int m = s_cnt;
    if (threadIdx.x == 0) blkcnt[blk] = m;           // unconditional: no init needed
    u64* kb = dense + (long)blk * STRIDE;
    for (int i = threadIdx.x; i < m; i += 256) kb[i] = stage[i];
}

// ---------------- Kernel 2: dual-rank radix select over block regions ----------------
// blocks 0-15 -> MSEL-th largest (Tsel), blocks 16-31 -> NSORT-th largest (Tsel2)
__global__ __launch_bounds__(1024) void k_select(const u64* __restrict__ dense,
                                                 const int* __restrict__ blkcnt,
                                                 u64* __restrict__ Tsel,
                                                 u64* __restrict__ Tsel2) {
    __shared__ int hist[2048];
    __shared__ int scnt[64];
    __shared__ int s_sel, s_gt;
    int blk = blockIdx.x;
    int b   = blk & (BDIM - 1);
    int rank = (blk < BDIM) ? MSEL : NSORT;
    u64* dst = (blk < BDIM) ? (Tsel + b) : (Tsel2 + b);
    int tid = threadIdx.x;

    if (tid < 64) scnt[tid] = blkcnt[b * 64 + tid];
    __syncthreads();
    int n = 0;
    for (int r = 0; r < 64; ++r) n += scnt[r];       // uniform LDS broadcast
    if (n <= rank) { if (tid == 0) *dst = 0ull; return; }

    const u64* kb = dense + (long)b * CAP_D;
    u64 prefix = 0, mask = 0;
    const int shifts[6] = {53, 42, 31, 20, 10, 0};
    const int bitsv [6] = {11, 11, 11, 11, 10, 10};

    for (int pass = 0; pass < 6; ++pass) {
        int shift = shifts[pass];
        int nb = 1 << bitsv[pass];
        if (tid < nb) hist[tid] = 0;
        if (tid + 1024 < nb) hist[tid + 1024] = 0;
        __syncthreads();
        // region-guided build (regions contiguous & coalesced)
        for (int r = 0; r < 64; ++r) {
            int cnt = scnt[r];
            const u64* kr = kb + r * STRIDE;
            for (int i = tid; i < cnt; i += 1024) {
                u64 k = kr[i];
                if ((k & mask) == prefix)
                    atomicAdd(&hist[(int)((k >> shift) & (u64)(nb - 1))], 1);
            }
        }
        __syncthreads();
        // suffix sum: hist[j] = count of elements in bins >= j (round-8/10 verified)
        for (int d = 1; d < nb; d <<= 1) {
            int v0 = 0, v1 = 0;
            if (tid < nb && tid + d < nb) v0 = hist[tid + d];
            if (tid + 1024 < nb && tid + 1024 + d < nb) v1 = hist[tid + 1024 + d];
            __syncthreads();
            if (tid < nb) hist[tid] += v0;
            if (tid + 1024 < nb) hist[tid + 1024] += v1;
            __syncthreads();
        }
        for (int j = tid; j < nb; j += 1024) {
            int c  = hist[j];
            int cn = (j + 1 < nb) ? hist[j + 1] : 0;
            if (c >= rank && cn < rank) { s_sel = j; s_gt = cn; }
        }
        __syncthreads();
        prefix |= ((u64)s_sel) << shift;
        mask   |= ((u64)(nb - 1)) << shift;
        rank   -= s_gt;
        __syncthreads();
    }
    if (tid == 0) *dst = prefix;
}

// ---------------- Kernel 3: gather + sort(top-1024) + decode + sorted-walk NMS (round-8/10 verified) ----------------
__global__ __launch_bounds__(TN) void k_nms(const u64* __restrict__ dense,
                                            const int* __restrict__ blkcnt,
                                            const u64* __restrict__ Tsel,
                                            const u64* __restrict__ Tsel2,
                                            const float* __restrict__ boxreg,
                                            const float* __restrict__ props,
                                            float* __restrict__ out) {
    __shared__ u64 skey[MSEL];          // 32 KB keys (sorted desc per batch)
    __shared__ float4 sbox[MSEL];       // 64 KB raw clipped boxes
    __shared__ float2 spack[MSEL];      // 32 KB {offset-area, (float)label}
    __shared__ int scnt[64];
    __shared__ int s_cnt, s_nacc;

    int b = blockIdx.x, tid = threadIdx.x;
    int lane = tid & 63, wid = tid >> 6;
    u64 T  = Tsel[b];
    u64 T2 = Tsel2[b];
    const u64* kb = dense + (long)b * CAP_D;
    u64 lm = (1ull << lane) - 1ull;

    if (tid < 64) scnt[tid] = blkcnt[b * 64 + tid];

    // accepted list: distributed over wave-0 lane registers (2 slots/lane, <=128)
    float ax1_0 = 0, ay1_0 = 0, ax2_0 = 0, ay2_0 = 0, aar_0 = 0;
    float ax1_1 = 0, ay1_1 = 0, ax2_1 = 0, ay2_1 = 0, aar_1 = 0;
    int alb_0 = -1, alb_1 = -1;
    u64 aky_0 = 0, aky_1 = 0;
    int nacc = 0;

    for (int bt = 0; bt < 2; ++bt) {
        if (bt == 1) {
            if (s_nacc >= KOUT || T2 == 0ull) break;   // uniform (post-barrier)
        }
        int SZ = bt ? MSEL : NSORT;

        // ---- zero + region-guided wave-aggregated gather ----
        for (int i = tid; i < SZ; i += TN) skey[i] = 0ull;
        if (tid == 0) s_cnt = 0;
        __syncthreads();
        for (int r = 0; r < 64; ++r) {
            int cnt = scnt[r];
            int cpad = (cnt + TN - 1) & ~(TN - 1);
            const u64* kr = kb + r * STRIDE;
            for (int i0 = tid; i0 < cpad; i0 += TN) {
                bool inb = (i0 < cnt);
                u64 k = inb ? kr[i0] : 0ull;
                bool pred = inb && (bt == 0 ? (k >= T2) : (k >= T && k < T2));
                u64 mb_ = __ballot(pred);
                int c2 = __popcll(mb_);
                int bp = 0;
                if (lane == 0 && c2) bp = atomicAdd(&s_cnt, c2);
                bp = __shfl(bp, 0);
                if (pred) {
                    int pos = bp + __popcll(mb_ & lm);
                    if (pos < SZ) skey[pos] = k;
                }
            }
        }
        __syncthreads();
        int mb = s_cnt; if (mb > SZ) mb = SZ;

        // ---- sort descending (zeros sink to end) ----
        if (bt == 0) {
            // register bitonic, 1 element/thread; shfl for j<64, LDS for j>=64 (round-8 verified)
            u64 r = skey[tid];
            for (int kk = 2; kk <= NSORT; kk <<= 1) {
                for (int j = kk >> 1; j; j >>= 1) {
                    u64 p;
                    if (j >= 64) {
                        skey[tid] = r;
                        __syncthreads();
                        p = skey[tid ^ j];
                        __syncthreads();
                    } else {
                        p = __shfl_xor(r, j);
                    }
                    bool lower = (tid & j) == 0;
                    bool desc  = ((tid & kk) == 0);
                    u64 mx = (r > p) ? r : p;
                    u64 mn = (r > p) ? p : r;
                    r = (lower == desc) ? mx : mn;
                }
            }
            skey[tid] = r;
            __syncthreads();
        } else {
            // LDS bitonic over MSEL (round-7 verified)
            for (int kk = 2; kk <= MSEL; kk <<= 1) {
                for (int j = kk >> 1; j > 0; j >>= 1) {
                    for (int t = tid; t < MSEL; t += TN) {
                        int l = t ^ j;
                        if (l > t) {
                            u64 a = skey[t], c = skey[l];
                            bool up = ((t & kk) == 0);
                            bool sw = up ? (a < c) : (a > c);
                            if (sw) { skey[t] = c; skey[l] = a; }
                        }
                    }
                    __syncthreads();
                }
            }
        }

        // ---- decode sorted candidates (round-6/7/8/10 verified expressions) ----
        for (int i = tid; i < mb; i += TN) {
            u64 k = skey[i];
            int flat = (int)(~(u32)k);
            int nidx = flat / NCM1;
            int c    = flat - nidx * NCM1 + 1;
            const float* pr = props + ((long)b * NP + nidx) * 4;
            float x1 = pr[0], y1 = pr[1], x2 = pr[2], y2 = pr[3];
            float w = x2 - x1, h = y2 - y1;
            float cx = x1 + 0.5f * w, cy = y1 + 0.5f * h;
            const float* rr = boxreg + (((long)b * NP + nidx) * NC + c) * 4;
            float dx = rr[0] / 10.0f, dy = rr[1] / 10.0f;
            float dw = fminf(rr[2] / 5.0f, DW_CLAMP_F);
            float dh = fminf(rr[3] / 5.0f, DW_CLAMP_F);
            // avoid FMA contraction: numpy does separate mul + add
            float pcx = __fadd_rn(__fmul_rn(dx, w), cx);
            float pcy = __fadd_rn(__fmul_rn(dy, h), cy);
            float pw  = __fmul_rn(expf(dw), w);
            float ph2 = __fmul_rn(expf(dh), h);
            float bx1 = fminf(fmaxf(pcx - 0.5f * pw, 0.0f), WF);
            float by1 = fminf(fmaxf(pcy - 0.5f * ph2, 0.0f), HF);
            float bx2 = fminf(fmaxf(pcx + 0.5f * pw, 0.0f), WF);
            float by2 = fminf(fmaxf(pcy + 0.5f * ph2, 0.0f), HF);
            sbox[i] = make_float4(bx1, by1, bx2, by2);
            // area on class-offset coords, exactly as reference computes it
            float offB = (float)c * OFFSETF;
            float ox1 = bx1 + offB, oy1 = by1 + offB;
            float ox2 = bx2 + offB, oy2 = by2 + offB;
            spack[i] = make_float2((ox2 - ox1) * (oy2 - oy1), (float)c);
        }
        __syncthreads();

        // ---- serial walk in sorted order (wave 0; register accepted list; round-8/10 verified) ----
        if (wid == 0) {
            float4 Bv = sbox[0];
            float2 pk = spack[0];
            u64    ck = skey[0];
            for (int i = 0; i < mb && nacc < KOUT; ++i) {
                int ip = (i + 1 < mb) ? i + 1 : i;
                float4 nBv = sbox[ip];          // prefetch next candidate
                float2 npk = spack[ip];
                u64    nck = skey[ip];

                float areaB = pk.x;
                float labf  = pk.y;
                float off   = __fmul_rn(labf, OFFSETF);
                bool conf = false;
                // slot 0 (accepted index = lane)
                if (lane < nacc && (float)alb_0 == labf) {
                    float op1x = __fadd_rn(fminf(ax2_0, Bv.z), off);
                    float op2x = __fadd_rn(fmaxf(ax1_0, Bv.x), off);
                    float iw = fmaxf(op1x - op2x, 0.0f);
                    float op1y = __fadd_rn(fminf(ay2_0, Bv.w), off);
                    float op2y = __fadd_rn(fmaxf(ay1_0, Bv.y), off);
                    float ih = fmaxf(op1y - op2y, 0.0f);
                    float inter = iw * ih;
                    float denom = areaB + aar_0 - inter + 1e-9f;
                    if (inter / denom > NMS_T) conf = true;
                }
                // slot 1 (accepted index = 64 + lane)
                if (64 + lane < nacc && (float)alb_1 == labf) {
                    float op1x = __fadd_rn(fminf(ax2_1, Bv.z), off);
                    float op2x = __fadd_rn(fmaxf(ax1_1, Bv.x), off);
                    float iw = fmaxf(op1x - op2x, 0.0f);
                    float op1y = __fadd_rn(fminf(ay2_1, Bv.w), off);
                    float op2y = __fadd_rn(fmaxf(ay1_1, Bv.y), off);
                    float ih = fmaxf(op1y - op2y, 0.0f);
                    float inter = iw * ih;
                    float denom = areaB + aar_1 - inter + 1e-9f;
                    if (inter / denom > NMS_T) conf = true;
                }
                if (__ballot(conf) == 0ull) {        // accept (uniform)
                    if (nacc < 64) {
                        if (lane == nacc) {
                            ax1_0 = Bv.x; ay1_0 = Bv.y; ax2_0 = Bv.z; ay2_0 = Bv.w;
                            aar_0 = areaB; alb_0 = (int)labf; aky_0 = ck;
                        }
                    } else {
                        if (lane == nacc - 64) {
                            ax1_1 = Bv.x; ay1_1 = Bv.y; ax2_1 = Bv.z; ay2_1 = Bv.w;
                            aar_1 = areaB; alb_1 = (int)labf; aky_1 = ck;
                        }
                    }
                    ++nacc;
                }
                Bv = nBv; pk = npk; ck = nck;
            }
            if (lane == 0) s_nacc = nacc;
        }
        __syncthreads();
    }

    // ---- emit outputs in acceptance order ----
    int na = s_nacc; if (na > KOUT) na = KOUT;
    if (wid == 0) {
        if (lane < na) {
            int a = lane;
            float* ob = out + ((long)b * KOUT + a) * 4;
            ob[0] = ax1_0; ob[1] = ay1_0; ob[2] = ax2_0; ob[3] = ay2_0;
            out[BDIM * KOUT * 4 + b * KOUT + a] = __uint_as_float((u32)(aky_0 >> 32));
            out[BDIM * KOUT * 5 + b * KOUT + a] = (float)alb_0;
            out[BDIM * KOUT * 6 + b * KOUT + a] = 1.0f;
        }
        if (64 + lane < na) {
            int a = 64 + lane;
            float* ob = out + ((long)b * KOUT + a) * 4;
            ob[0] = ax1_1; ob[1] = ay1_1; ob[2] = ax2_1; ob[3] = ay2_1;
            out[BDIM * KOUT * 4 + b * KOUT + a] = __uint_as_float((u32)(aky_1 >> 32));
            out[BDIM * KOUT * 5 + b * KOUT + a] = (float)alb_1;
            out[BDIM * KOUT * 6 + b * KOUT + a] = 1.0f;
        }
    }
    for (int a = tid; a < KOUT; a += TN) {
        if (a >= na) {
            float* ob = out + ((long)b * KOUT + a) * 4;
            ob[0] = 0.0f; ob[1] = 0.0f; ob[2] = 0.0f; ob[3] = 0.0f;
            out[BDIM * KOUT * 4 + b * KOUT + a] = 0.0f;
            out[BDIM * KOUT * 5 + b * KOUT + a] = -1.0f;
            out[BDIM * KOUT * 6 + b * KOUT + a] = 0.0f;
        }
    }
}

extern "C" void kernel_launch(void* const* d_in, const int* in_sizes, int n_in,
                              void* d_out, int out_size, void* d_ws, size_t ws_size,
                              hipStream_t stream) {
    const float* logits = (const float*)d_in[0];
    const float* boxreg = (const float*)d_in[1];
    const float* props  = (const float*)d_in[2];
    float* out = (float*)d_out;

    char* ws = (char*)d_ws;
    int* blkcnt = (int*)(ws + 0);                 // 1024*4 = 4 KB
    u64* Tsel   = (u64*)(ws + 4096);              // 128 B
    u64* Tsel2  = (u64*)(ws + 4352);              // 128 B
    u64* dense  = (u64*)(ws + 4608);              // 1024*1216*8 = 9.96 MB

    k_soft<<<(BDIM * NP) / RPB, 256, 0, stream>>>(logits, dense, blkcnt);
    k_select<<<2 * BDIM, 1024, 0, stream>>>(dense, blkcnt, Tsel, Tsel2);
    k_nms<<<BDIM, TN, 0, stream>>>(dense, blkcnt, Tsel, Tsel2, boxreg, props, out);
}

// Round 12
// 114.010 us; speedup vs baseline: 1.7596x; 1.7596x over previous
//
#include <hip/hip_runtime.h>

typedef unsigned long long u64;
typedef unsigned int u32;

#define BDIM 16
#define NP   4096
#define NC   91
#define NCM1 90
#define MSEL 4096       // top-M per image (reference M)
#define NSORT 1024      // batch-0 sorted prefix size
#define KOUT 100
#define RSLOT 19        // max candidates per row (scores sum to 1, >0.05 => <=19)
#define CAP_D (NP * RSLOT)   // 77824: provable per-image max -> no overflow possible
#define SCORE_T 0.05f
#define NMS_T   0.5f
#define OFFSETF 10000.0f
#define DW_CLAMP_F 4.135166556742356f
#define WF 1333.0f
#define HF 800.0f

#define TN 1024
#define NW (TN / 64)      // 16 waves
#define RPB 64            // rows per k_soft block (64 blocks per image)

// ---------------- Kernel 0: zero the 16 per-image counters (replaces in-graph memset node) ----------------
__global__ __launch_bounds__(64) void k_zero(int* __restrict__ gcount) {
    if (threadIdx.x < BDIM) gcount[threadIdx.x] = 0;
}

// ---------------- Kernel 1: softmax -> dense candidates (round-10 verified) ----------------
// Dense order is nondeterministic but the MULTISET is deterministic; downstream
// histogram (commutative) and bitonic sort (distinct keys) canonicalize -> output bit-deterministic.
__global__ __launch_bounds__(256) void k_soft(const float* __restrict__ logits,
                                              u64* __restrict__ dense,
                                              int* __restrict__ gcount) {
    __shared__ u64 stage[RPB * RSLOT];   // 1216 keys max (block's provable cap) = 9.5 KB
    __shared__ int s_cnt, s_base;

    int blk  = blockIdx.x;               // 1024 blocks; 64 consecutive rows each
    int b    = blk >> 6;                 // image index (64 blocks per image)
    int lane = threadIdx.x & 63;
    int wid  = threadIdx.x >> 6;

    if (threadIdx.x == 0) s_cnt = 0;
    __syncthreads();

    u64 lm = (1ull << lane) - 1ull;
    for (int it = 0; it < RPB / 4; ++it) {
        int row = blk * RPB + it * 4 + wid;          // one wave per row
        const float* lg = logits + (long)row * NC;

        float v0 = lg[lane];
        float v1 = (lane < NC - 64) ? lg[64 + lane] : -3.0e38f;
        float mx = fmaxf(v0, v1);
#pragma unroll
        for (int s = 32; s; s >>= 1) mx = fmaxf(mx, __shfl_xor(mx, s));
        float e0 = expf(v0 - mx);
        float e1 = (lane < NC - 64) ? expf(v1 - mx) : 0.0f;
        float sum = e0 + e1;
#pragma unroll
        for (int s = 32; s; s >>= 1) sum += __shfl_xor(sum, s);

        float s0 = e0 / sum;
        float s1 = e1 / sum;

        int n = row & (NP - 1);
        bool p0 = (lane >= 1) && (s0 > SCORE_T);          // class = lane (skip background 0)
        bool p1 = (lane < NC - 64) && (s1 > SCORE_T);     // class = 64 + lane
        u64 m0 = __ballot(p0);
        u64 m1 = __ballot(p1);
        int c0  = __popcll(m0);
        int cnt = c0 + __popcll(m1);

        int base = 0;
        if (lane == 0 && cnt) base = atomicAdd(&s_cnt, cnt);   // LDS atomic, 1/wave/row
        base = __shfl(base, 0);
        if (p0) {
            int pos  = base + __popcll(m0 & lm);
            int flat = n * NCM1 + (lane - 1);
            stage[pos] = ((u64)__float_as_uint(s0) << 32) | (u32)(~(u32)flat);
        }
        if (p1) {
            int pos  = base + c0 + __popcll(m1 & lm);
            int flat = n * NCM1 + (64 + lane - 1);
            stage[pos] = ((u64)__float_as_uint(s1) << 32) | (u32)(~(u32)flat);
        }
    }
    __syncthreads();

    if (threadIdx.x == 0) s_base = atomicAdd(&gcount[b], s_cnt);  // 64 atomics/image total
    __syncthreads();
    int m = s_cnt, base = s_base;
    u64* kb = dense + (long)b * CAP_D + base;        // base+m <= 77824 = CAP_D provably
    for (int i = threadIdx.x; i < m; i += 256) kb[i] = stage[i];
}

// ---------------- Kernel 2: dual-rank radix select over dense (round-8/10 verified) ----------------
// blocks 0-15 -> MSEL-th largest (Tsel), blocks 16-31 -> NSORT-th largest (Tsel2)
__global__ __launch_bounds__(1024) void k_select(const u64* __restrict__ dense,
                                                 const int* __restrict__ nsel,
                                                 u64* __restrict__ Tsel,
                                                 u64* __restrict__ Tsel2) {
    __shared__ int hist[2048];
    __shared__ int s_sel, s_gt;
    int blk = blockIdx.x;
    int b   = blk & (BDIM - 1);
    int rank = (blk < BDIM) ? MSEL : NSORT;
    u64* dst = (blk < BDIM) ? (Tsel + b) : (Tsel2 + b);
    int tid = threadIdx.x;
    int n = nsel[b]; if (n > CAP_D) n = CAP_D;
    if (n <= rank) { if (tid == 0) *dst = 0ull; return; }

    const u64* kb = dense + (long)b * CAP_D;
    u64 prefix = 0, mask = 0;
    const int shifts[6] = {53, 42, 31, 20, 10, 0};
    const int bitsv [6] = {11, 11, 11, 11, 10, 10};

    for (int pass = 0; pass < 6; ++pass) {
        int shift = shifts[pass];
        int nb = 1 << bitsv[pass];
        if (tid < nb) hist[tid] = 0;
        if (tid + 1024 < nb) hist[tid + 1024] = 0;
        __syncthreads();
        for (int i = tid; i < n; i += 1024) {
            u64 k = kb[i];
            if ((k & mask) == prefix)
                atomicAdd(&hist[(int)((k >> shift) & (u64)(nb - 1))], 1);
        }
        __syncthreads();
        // suffix sum: hist[j] = count of elements in bins >= j
        for (int d = 1; d < nb; d <<= 1) {
            int v0 = 0, v1 = 0;
            if (tid < nb && tid + d < nb) v0 = hist[tid + d];
            if (tid + 1024 < nb && tid + 1024 + d < nb) v1 = hist[tid + 1024 + d];
            __syncthreads();
            if (tid < nb) hist[tid] += v0;
            if (tid + 1024 < nb) hist[tid + 1024] += v1;
            __syncthreads();
        }
        for (int j = tid; j < nb; j += 1024) {
            int c  = hist[j];
            int cn = (j + 1 < nb) ? hist[j + 1] : 0;
            if (c >= rank && cn < rank) { s_sel = j; s_gt = cn; }
        }
        __syncthreads();
        prefix |= ((u64)s_sel) << shift;
        mask   |= ((u64)(nb - 1)) << shift;
        rank   -= s_gt;
        __syncthreads();
    }
    if (tid == 0) *dst = prefix;
}

// ---------------- Kernel 3: gather + sort(top-1024) + decode + sorted-walk NMS (round-8/10 verified) ----------------
__global__ __launch_bounds__(TN) void k_nms(const u64* __restrict__ dense,
                                            const int* __restrict__ nsel,
                                            const u64* __restrict__ Tsel,
                                            const u64* __restrict__ Tsel2,
                                            const float* __restrict__ boxreg,
                                            const float* __restrict__ props,
                                            float* __restrict__ out) {
    __shared__ u64 skey[MSEL];          // 32 KB keys (sorted desc per batch)
    __shared__ float4 sbox[MSEL];       // 64 KB raw clipped boxes
    __shared__ float2 spack[MSEL];      // 32 KB {offset-area, (float)label}
    __shared__ int s_cnt, s_nacc;

    int b = blockIdx.x, tid = threadIdx.x;
    int lane = tid & 63, wid = tid >> 6;
    int n = nsel[b]; if (n > CAP_D) n = CAP_D;
    u64 T  = Tsel[b];
    u64 T2 = Tsel2[b];
    const u64* kb = dense + (long)b * CAP_D;
    u64 lm = (1ull << lane) - 1ull;
    int npad = (n + TN - 1) & ~(TN - 1);

    // accepted list: distributed over wave-0 lane registers (2 slots/lane, <=128)
    float ax1_0 = 0, ay1_0 = 0, ax2_0 = 0, ay2_0 = 0, aar_0 = 0;
    float ax1_1 = 0, ay1_1 = 0, ax2_1 = 0, ay2_1 = 0, aar_1 = 0;
    int alb_0 = -1, alb_1 = -1;
    u64 aky_0 = 0, aky_1 = 0;
    int nacc = 0;

    for (int bt = 0; bt < 2; ++bt) {
        if (bt == 1) {
            if (s_nacc >= KOUT || T2 == 0ull) break;   // uniform (post-barrier)
        }
        int SZ = bt ? MSEL : NSORT;

        // ---- zero + wave-aggregated flat gather (round-8 verified) ----
        for (int i = tid; i < SZ; i += TN) skey[i] = 0ull;
        if (tid == 0) s_cnt = 0;
        __syncthreads();
        for (int i0 = tid; i0 < npad; i0 += TN) {
            bool inb = (i0 < n);
            u64 k = inb ? kb[i0] : 0ull;
            bool pred = inb && (bt == 0 ? (k >= T2) : (k >= T && k < T2));
            u64 mb_ = __ballot(pred);
            int cnt = __popcll(mb_);
            int bp = 0;
            if (lane == 0 && cnt) bp = atomicAdd(&s_cnt, cnt);
            bp = __shfl(bp, 0);
            if (pred) {
                int pos = bp + __popcll(mb_ & lm);
                if (pos < SZ) skey[pos] = k;
            }
        }
        __syncthreads();
        int mb = s_cnt; if (mb > SZ) mb = SZ;

        // ---- sort descending (zeros sink to end) ----
        if (bt == 0) {
            // register bitonic, 1 element/thread; shfl for j<64, LDS for j>=64 (round-8 verified)
            u64 r = skey[tid];
            for (int kk = 2; kk <= NSORT; kk <<= 1) {
                for (int j = kk >> 1; j; j >>= 1) {
                    u64 p;
                    if (j >= 64) {
                        skey[tid] = r;
                        __syncthreads();
                        p = skey[tid ^ j];
                        __syncthreads();
                    } else {
                        p = __shfl_xor(r, j);
                    }
                    bool lower = (tid & j) == 0;
                    bool desc  = ((tid & kk) == 0);
                    u64 mx = (r > p) ? r : p;
                    u64 mn = (r > p) ? p : r;
                    r = (lower == desc) ? mx : mn;
                }
            }
            skey[tid] = r;
            __syncthreads();
        } else {
            // LDS bitonic over MSEL (round-7 verified)
            for (int kk = 2; kk <= MSEL; kk <<= 1) {
                for (int j = kk >> 1; j > 0; j >>= 1) {
                    for (int t = tid; t < MSEL; t += TN) {
                        int l = t ^ j;
                        if (l > t) {
                            u64 a = skey[t], c = skey[l];
                            bool up = ((t & kk) == 0);
                            bool sw = up ? (a < c) : (a > c);
                            if (sw) { skey[t] = c; skey[l] = a; }
                        }
                    }
                    __syncthreads();
                }
            }
        }

        // ---- decode sorted candidates (round-6/7/8 verified expressions) ----
        for (int i = tid; i < mb; i += TN) {
            u64 k = skey[i];
            int flat = (int)(~(u32)k);
            int nidx = flat / NCM1;
            int c    = flat - nidx * NCM1 + 1;
            const float* pr = props + ((long)b * NP + nidx) * 4;
            float x1 = pr[0], y1 = pr[1], x2 = pr[2], y2 = pr[3];
            float w = x2 - x1, h = y2 - y1;
            float cx = x1 + 0.5f * w, cy = y1 + 0.5f * h;
            const float* rr = boxreg + (((long)b * NP + nidx) * NC + c) * 4;
            float dx = rr[0] / 10.0f, dy = rr[1] / 10.0f;
            float dw = fminf(rr[2] / 5.0f, DW_CLAMP_F);
            float dh = fminf(rr[3] / 5.0f, DW_CLAMP_F);
            // avoid FMA contraction: numpy does separate mul + add
            float pcx = __fadd_rn(__fmul_rn(dx, w), cx);
            float pcy = __fadd_rn(__fmul_rn(dy, h), cy);
            float pw  = __fmul_rn(expf(dw), w);
            float ph2 = __fmul_rn(expf(dh), h);
            float bx1 = fminf(fmaxf(pcx - 0.5f * pw, 0.0f), WF);
            float by1 = fminf(fmaxf(pcy - 0.5f * ph2, 0.0f), HF);
            float bx2 = fminf(fmaxf(pcx + 0.5f * pw, 0.0f), WF);
            float by2 = fminf(fmaxf(pcy + 0.5f * ph2, 0.0f), HF);
            sbox[i] = make_float4(bx1, by1, bx2, by2);
            // area on class-offset coords, exactly as reference computes it
            float offB = (float)c * OFFSETF;
            float ox1 = bx1 + offB, oy1 = by1 + offB;
            float ox2 = bx2 + offB, oy2 = by2 + offB;
            spack[i] = make_float2((ox2 - ox1) * (oy2 - oy1), (float)c);
        }
        __syncthreads();

        // ---- serial walk in sorted order (wave 0; register accepted list; round-8 verified) ----
        if (wid == 0) {
            float4 Bv = sbox[0];
            float2 pk = spack[0];
            u64    ck = skey[0];
            for (int i = 0; i < mb && nacc < KOUT; ++i) {
                int ip = (i + 1 < mb) ? i + 1 : i;
                float4 nBv = sbox[ip];          // prefetch next candidate
                float2 npk = spack[ip];
                u64    nck = skey[ip];

                float areaB = pk.x;
                float labf  = pk.y;
                float off   = __fmul_rn(labf, OFFSETF);
                bool conf = false;
                // slot 0 (accepted index = lane)
                if (lane < nacc && (float)alb_0 == labf) {
                    float op1x = __fadd_rn(fminf(ax2_0, Bv.z), off);
                    float op2x = __fadd_rn(fmaxf(ax1_0, Bv.x), off);
                    float iw = fmaxf(op1x - op2x, 0.0f);
                    float op1y = __fadd_rn(fminf(ay2_0, Bv.w), off);
                    float op2y = __fadd_rn(fmaxf(ay1_0, Bv.y), off);
                    float ih = fmaxf(op1y - op2y, 0.0f);
                    float inter = iw * ih;
                    float denom = areaB + aar_0 - inter + 1e-9f;
                    if (inter / denom > NMS_T) conf = true;
                }
                // slot 1 (accepted index = 64 + lane)
                if (64 + lane < nacc && (float)alb_1 == labf) {
                    float op1x = __fadd_rn(fminf(ax2_1, Bv.z), off);
                    float op2x = __fadd_rn(fmaxf(ax1_1, Bv.x), off);
                    float iw = fmaxf(op1x - op2x, 0.0f);
                    float op1y = __fadd_rn(fminf(ay2_1, Bv.w), off);
                    float op2y = __fadd_rn(fmaxf(ay1_1, Bv.y), off);
                    float ih = fmaxf(op1y - op2y, 0.0f);
                    float inter = iw * ih;
                    float denom = areaB + aar_1 - inter + 1e-9f;
                    if (inter / denom > NMS_T) conf = true;
                }
                if (__ballot(conf) == 0ull) {        // accept (uniform)
                    if (nacc < 64) {
                        if (lane == nacc) {
                            ax1_0 = Bv.x; ay1_0 = Bv.y; ax2_0 = Bv.z; ay2_0 = Bv.w;
                            aar_0 = areaB; alb_0 = (int)labf; aky_0 = ck;
                        }
                    } else {
                        if (lane == nacc - 64) {
                            ax1_1 = Bv.x; ay1_1 = Bv.y; ax2_1 = Bv.z; ay2_1 = Bv.w;
                            aar_1 = areaB; alb_1 = (int)labf; aky_1 = ck;
                        }
                    }
                    ++nacc;
                }
                Bv = nBv; pk = npk; ck = nck;
            }
            if (lane == 0) s_nacc = nacc;
        }
        __syncthreads();
    }

    // ---- emit outputs in acceptance order ----
    int na = s_nacc; if (na > KOUT) na = KOUT;
    if (wid == 0) {
        if (lane < na) {
            int a = lane;
            float* ob = out + ((long)b * KOUT + a) * 4;
            ob[0] = ax1_0; ob[1] = ay1_0; ob[2] = ax2_0; ob[3] = ay2_0;
            out[BDIM * KOUT * 4 + b * KOUT + a] = __uint_as_float((u32)(aky_0 >> 32));
            out[BDIM * KOUT * 5 + b * KOUT + a] = (float)alb_0;
            out[BDIM * KOUT * 6 + b * KOUT + a] = 1.0f;
        }
        if (64 + lane < na) {
            int a = 64 + lane;
            float* ob = out + ((long)b * KOUT + a) * 4;
            ob[0] = ax1_1; ob[1] = ay1_1; ob[2] = ax2_1; ob[3] = ay2_1;
            out[BDIM * KOUT * 4 + b * KOUT + a] = __uint_as_float((u32)(aky_1 >> 32));
            out[BDIM * KOUT * 5 + b * KOUT + a] = (float)alb_1;
            out[BDIM * KOUT * 6 + b * KOUT + a] = 1.0f;
        }
    }
    for (int a = tid; a < KOUT; a += TN) {
        if (a >= na) {
            float* ob = out + ((long)b * KOUT + a) * 4;
            ob[0] = 0.0f; ob[1] = 0.0f; ob[2] = 0.0f; ob[3] = 0.0f;
            out[BDIM * KOUT * 4 + b * KOUT + a] = 0.0f;
            out[BDIM * KOUT * 5 + b * KOUT + a] = -1.0f;
            out[BDIM * KOUT * 6 + b * KOUT + a] = 0.0f;
        }
    }
}

extern "C" void kernel_launch(void* const* d_in, const int* in_sizes, int n_in,
                              void* d_out, int out_size, void* d_ws, size_t ws_size,
                              hipStream_t stream) {
    const float* logits = (const float*)d_in[0];
    const float* boxreg = (const float*)d_in[1];
    const float* props  = (const float*)d_in[2];
    float* out = (float*)d_out;

    char* ws = (char*)d_ws;
    int* gcount = (int*)(ws + 0);                 // 64 B
    u64* Tsel   = (u64*)(ws + 256);               // 128 B
    u64* Tsel2  = (u64*)(ws + 512);               // 128 B
    u64* dense  = (u64*)(ws + 1024);              // 16*77824*8 = 9.96 MB

    k_zero<<<1, 64, 0, stream>>>(gcount);
    k_soft<<<(BDIM * NP) / RPB, 256, 0, stream>>>(logits, dense, gcount);
    k_select<<<2 * BDIM, 1024, 0, stream>>>(dense, gcount, Tsel, Tsel2);
    k_nms<<<BDIM, TN, 0, stream>>>(dense, gcount, Tsel, Tsel2, boxreg, props, out);
}